// Round 1
// baseline (133.257 us; speedup 1.0000x reference)
//
#include <hip/hip_runtime.h>

// RoIAlign-3D: x[2,256,16,64,64] f32, rois[128,5] -> out[128,256,16,7,7] f32
// Schedule: pre-kernel builds per-ROI separable lerp tables + per-image ROI
// lists in d_ws; main kernel = 1 block per (image, c*t plane), stages the
// 64x64 plane in LDS (input read exactly once), computes all matching ROIs.

#define LP 68               // LDS row pitch in floats (68*4 % 16 == 0 -> float4 stores aligned)
#define YT 258              // y-table base (words): 2 counts + 2*128 list
#define XT (YT + 128 * 42)  // x-table base; per-roi: 14 entries * 3 words

__global__ __launch_bounds__(128) void pooler_pre(const float* __restrict__ rois,
                                                  int* __restrict__ wi,
                                                  float* __restrict__ wf) {
    int k = threadIdx.x;  // one thread per ROI, k in [0,128)
    float x1 = rois[5 * k + 1] * 0.25f, y1 = rois[5 * k + 2] * 0.25f;
    float x2 = rois[5 * k + 3] * 0.25f, y2 = rois[5 * k + 4] * 0.25f;
    float rw = fmaxf(x2 - x1, 1.0f), rh = fmaxf(y2 - y1, 1.0f);
    float bw = rw * (1.0f / 14.0f), bh = rh * (1.0f / 14.0f);
    for (int i = 0; i < 14; ++i) {
        // y side: fold boundary mask into weights
        float ys = y1 + ((float)i + 0.5f) * bh;
        float my = (ys >= -1.0f && ys <= 64.0f) ? 1.0f : 0.0f;
        float yc = fminf(fmaxf(ys, 0.0f), 63.0f);
        int y0 = (int)yc; if (y0 > 62) y0 = 62;   // yc>=0 so (int) == floor
        float ly = yc - (float)y0;
        int o = YT + k * 42 + i * 3;
        wi[o]     = y0 * LP;                       // pre-multiplied LDS row offset
        wf[o + 1] = (1.0f - ly) * my;
        wf[o + 2] = ly * my;
        // x side: fold mask AND the 1/4 sample-average
        float xs = x1 + ((float)i + 0.5f) * bw;
        float mx = (xs >= -1.0f && xs <= 64.0f) ? 1.0f : 0.0f;
        float xc = fminf(fmaxf(xs, 0.0f), 63.0f);
        int x0 = (int)xc; if (x0 > 62) x0 = 62;
        float lx = xc - (float)x0;
        o = XT + k * 42 + i * 3;
        wi[o]     = x0;
        wf[o + 1] = (1.0f - lx) * mx * 0.25f;
        wf[o + 2] = lx * mx * 0.25f;
    }
    if (k == 0) {  // per-image ROI lists (serial, 128 iters, trivial)
        int c0 = 0, c1 = 0;
        for (int j = 0; j < 128; ++j) {
            int b = (int)rois[5 * j];
            if (b == 0) wi[2 + c0++] = j;
            else        wi[2 + 128 + c1++] = j;
        }
        wi[0] = c0; wi[1] = c1;
    }
}

__global__ __launch_bounds__(256) void pooler_main(const float* __restrict__ x,
                                                   const int* __restrict__ wi,
                                                   const float* __restrict__ wf,
                                                   float* __restrict__ out) {
    __shared__ float lds[64 * LP];
    const int tid = threadIdx.x;
    const int b = blockIdx.x >> 12;        // image
    const int plane = blockIdx.x & 4095;   // c*16 + t
    const int c = plane >> 4, t = plane & 15;

    // Stage the 64x64 plane: coalesced float4 loads, input read exactly once.
    const float4* src = (const float4*)(x + (((size_t)(b << 12) + plane) << 12));
    #pragma unroll
    for (int j = 0; j < 4; ++j) {
        int g = tid + j * 256;             // float4 index, 0..1023
        float4 v = src[g];
        int y = g >> 4, x4 = (g & 15) << 2;
        *(float4*)&lds[y * LP + x4] = v;
    }
    __syncthreads();

    const int nroi = wi[b];
    const int* list = wi + 2 + (b << 7);
    const int total = nroi * 49;
    for (int w = tid; w < total; w += 256) {
        int r = w / 49, o = w - r * 49;
        int k = list[r];
        int ph = o / 7, pw = o - ph * 7;
        int yb = YT + k * 42 + ph * 6;     // entries for sy=0,1
        int xb = XT + k * 42 + pw * 6;     // entries for sx=0,1
        float acc = 0.0f;
        #pragma unroll
        for (int sy = 0; sy < 2; ++sy) {
            int   yo = wi[yb + sy * 3];
            float hy = wf[yb + sy * 3 + 1], lyw = wf[yb + sy * 3 + 2];
            #pragma unroll
            for (int sx = 0; sx < 2; ++sx) {
                int   x0 = wi[xb + sx * 3];
                float hx = wf[xb + sx * 3 + 1], lxw = wf[xb + sx * 3 + 2];
                const float* p = lds + yo + x0;
                float v00 = p[0], v01 = p[1], v10 = p[LP], v11 = p[LP + 1];
                acc += hy * (hx * v00 + lxw * v01) + lyw * (hx * v10 + lxw * v11);
            }
        }
        out[(((k << 8) + c) * 16 + t) * 49 + o] = acc;
    }
}

extern "C" void kernel_launch(void* const* d_in, const int* in_sizes, int n_in,
                              void* d_out, int out_size, void* d_ws, size_t ws_size,
                              hipStream_t stream) {
    const float* x    = (const float*)d_in[0];
    const float* rois = (const float*)d_in[1];
    float* out = (float*)d_out;
    int*   wi  = (int*)d_ws;
    float* wf  = (float*)d_ws;
    pooler_pre<<<1, 128, 0, stream>>>(rois, wi, wf);
    pooler_main<<<2 * 256 * 16, 256, 0, stream>>>(x, wi, wf, out);
}

// Round 2
// 91.846 us; speedup vs baseline: 1.4509x; 1.4509x over previous
//
#include <hip/hip_runtime.h>

// RoIAlign-3D: x[2,256,16,64,64] f32, rois[128,5] -> out[128,256,16,7,7] f32
// R2: drop the global lerp tables (they were a dependent-load latency chain);
// recompute sampling metadata in-register from LDS-staged ROI boxes.
// One block per (image, c*t plane); plane staged in LDS, input read once.

#define LP 68  // LDS row pitch in floats (68*4 % 16 == 0 -> aligned float4 stores; +4 bank skew/row)

__global__ __launch_bounds__(64) void pooler_pre(const float* __restrict__ rois,
                                                 int* __restrict__ wi) {
    if (threadIdx.x == 0) {   // per-image ROI lists; zero-fill tails (safe dummy reads later)
        int c0 = 0, c1 = 0;
        for (int j = 0; j < 128; ++j) {
            int b = (int)rois[5 * j];
            if (b == 0) wi[2 + c0++] = j;
            else        wi[2 + 128 + c1++] = j;
        }
        wi[0] = c0; wi[1] = c1;
        for (int j = c0; j < 128; ++j) wi[2 + j] = 0;
        for (int j = c1; j < 128; ++j) wi[2 + 128 + j] = 0;
    }
}

__global__ __launch_bounds__(256) void pooler_main(const float* __restrict__ x,
                                                   const float* __restrict__ rois,
                                                   const int* __restrict__ wi,
                                                   float* __restrict__ out) {
    __shared__ float plane[64 * LP];
    __shared__ float rbox[128][4];   // x1, y1, bin_w, bin_h (pre-scaled)
    __shared__ int   rlist[128];

    const int tid = threadIdx.x;
    const int b  = blockIdx.x >> 12;
    const int pl = blockIdx.x & 4095;          // c*16 + t

    // Stage the 64x64 plane: coalesced float4, input read exactly once.
    const float4* src = (const float4*)(x + (((size_t)(b << 12) + pl) << 12));
    #pragma unroll
    for (int j = 0; j < 4; ++j) {
        int g = tid + j * 256;
        float4 v = src[g];
        *(float4*)&plane[(g >> 4) * LP + ((g & 15) << 2)] = v;
    }
    // Stage ROI boxes + list for this image.
    const int nroi = wi[b];
    if (tid < 128) {
        int j = wi[2 + (b << 7) + tid];
        rlist[tid] = j;
        float x1 = rois[5 * j + 1] * 0.25f, y1 = rois[5 * j + 2] * 0.25f;
        float x2 = rois[5 * j + 3] * 0.25f, y2 = rois[5 * j + 4] * 0.25f;
        rbox[tid][0] = x1;
        rbox[tid][1] = y1;
        rbox[tid][2] = fmaxf(x2 - x1, 1.0f) * (1.0f / 14.0f);
        rbox[tid][3] = fmaxf(y2 - y1, 1.0f) * (1.0f / 14.0f);
    }
    __syncthreads();

    const int c = pl >> 4, t = pl & 15;
    const int total = nroi * 49;
    for (int w = tid; w < total; w += 256) {
        int r = w / 49, o = w - r * 49;
        int ph = o / 7, pw = o - ph * 7;
        int k = rlist[r];
        float x1 = rbox[r][0], y1 = rbox[r][1], bw = rbox[r][2], bh = rbox[r][3];

        int yoff[2], xoff[2];
        float wyh[2], wyl[2], wxh[2], wxl[2];
        #pragma unroll
        for (int s = 0; s < 2; ++s) {
            float ys = y1 + ((float)(2 * ph + s) + 0.5f) * bh;
            float my = (ys >= -1.0f && ys <= 64.0f) ? 1.0f : 0.0f;
            float yc = fminf(fmaxf(ys, 0.0f), 63.0f);
            int y0 = (int)yc; y0 = y0 > 62 ? 62 : y0;
            float ly = yc - (float)y0;
            yoff[s] = y0 * LP;
            wyh[s]  = (1.0f - ly) * my;
            wyl[s]  = ly * my;

            float xs = x1 + ((float)(2 * pw + s) + 0.5f) * bw;
            float mx = (xs >= -1.0f && xs <= 64.0f) ? 1.0f : 0.0f;
            float xc = fminf(fmaxf(xs, 0.0f), 63.0f);
            int x0 = (int)xc; x0 = x0 > 62 ? 62 : x0;
            float lx = xc - (float)x0;
            xoff[s] = x0;
            wxh[s]  = (1.0f - lx) * mx * 0.25f;  // fold 2x2-sample mean
            wxl[s]  = lx * mx * 0.25f;
        }

        float acc = 0.0f;
        #pragma unroll
        for (int sy = 0; sy < 2; ++sy)
            #pragma unroll
            for (int sx = 0; sx < 2; ++sx) {
                const float* p = plane + yoff[sy] + xoff[sx];
                acc += wyh[sy] * (wxh[sx] * p[0]  + wxl[sx] * p[1])
                     + wyl[sy] * (wxh[sx] * p[LP] + wxl[sx] * p[LP + 1]);
            }
        out[(((k << 8) + c) * 16 + t) * 49 + o] = acc;
    }
}

extern "C" void kernel_launch(void* const* d_in, const int* in_sizes, int n_in,
                              void* d_out, int out_size, void* d_ws, size_t ws_size,
                              hipStream_t stream) {
    const float* x    = (const float*)d_in[0];
    const float* rois = (const float*)d_in[1];
    float* out = (float*)d_out;
    int*   wi  = (int*)d_ws;
    pooler_pre<<<1, 64, 0, stream>>>(rois, wi);
    pooler_main<<<2 * 256 * 16, 256, 0, stream>>>(x, rois, wi, out);
}

// Round 3
// 70.211 us; speedup vs baseline: 1.8979x; 1.3081x over previous
//
#include <hip/hip_runtime.h>

// RoIAlign-3D: x[2,256,16,64,64] f32, rois[128,5] -> out[128,256,16,7,7] f32
// R3: factored 3x3-footprint form. bin_w,bin_h <= 1.0 => the 2x2 sample mean
// per output factors into (3-tap y-weights) x (3-tap x-weights) over a 3x3
// texel window. 6x ds_read_b64 per output instead of 16x ds_read_b32.
// Block = 2 planes (c, t-pair); thread task = (roi, t-half, ph) -> 7 outputs.

#define LP  68            // LDS row pitch (words): even, 16B-aligned rows, +4 bank skew
#define LPH 34            // LP/2 (float2 pitch)
#define PLW (65 * LP)     // 64 rows + 1 zero pad row

__global__ __launch_bounds__(128) void pooler_pre(const float* __restrict__ rois,
                                                  int* __restrict__ wi) {
    __shared__ int sb[128];
    int tid = threadIdx.x;
    sb[tid] = (int)rois[5 * tid];
    __syncthreads();
    if (tid == 0) {
        int c0 = 0, c1 = 0;
        for (int j = 0; j < 128; ++j) {
            if (sb[j] == 0) wi[2 + c0++] = j;
            else            wi[2 + 128 + c1++] = j;
        }
        wi[0] = c0; wi[1] = c1;
        for (int j = c0; j < 128; ++j) wi[2 + j] = 0;
        for (int j = c1; j < 128; ++j) wi[2 + 128 + j] = 0;
    }
}

__global__ __launch_bounds__(512) void pooler_main(const float* __restrict__ x,
                                                   const float* __restrict__ rois,
                                                   const int* __restrict__ wi,
                                                   float* __restrict__ out) {
    __shared__ float plane[2][PLW];
    __shared__ float rb[128][4];      // x1, y1, bin_w, bin_h (pre-scaled)
    __shared__ int   rlist[128];
    __shared__ int   snroi;

    const int tid = threadIdx.x;
    const int bid = blockIdx.x;
    const int b   = bid >> 11;        // image
    const int c   = (bid >> 3) & 255;
    const int tp  = bid & 7;          // t-pair

    // Stage two contiguous planes: coalesced float4, input read exactly once.
    const float4* src = (const float4*)(x + ((((size_t)b * 256 + c) * 16 + 2 * tp) << 12));
    #pragma unroll
    for (int j = 0; j < 4; ++j) {
        int g = tid + j * 512;        // float4 index 0..2047
        float4 v = src[g];
        int pi = g >> 10, gg = g & 1023;
        *(float4*)&plane[pi][(gg >> 4) * LP + ((gg & 15) << 2)] = v;
    }
    // Zero the pads (cols 64..67 of rows 0..64, and pad row 64): window reads
    // may touch them; their weights are true zeros so 0*0=0 (no NaN).
    if (tid < 162) {
        int pi = tid >= 81, u = pi ? tid - 81 : tid;
        float4 z = make_float4(0.f, 0.f, 0.f, 0.f);
        if (u < 65) *(float4*)&plane[pi][u * LP + 64] = z;
        else        *(float4*)&plane[pi][64 * LP + ((u - 65) << 2)] = z;
    }
    if (tid < 128) {
        int j = wi[2 + (b << 7) + tid];
        rlist[tid] = j;
        float x1 = rois[5 * j + 1] * 0.25f, y1 = rois[5 * j + 2] * 0.25f;
        float x2 = rois[5 * j + 3] * 0.25f, y2 = rois[5 * j + 4] * 0.25f;
        rb[tid][0] = x1;
        rb[tid][1] = y1;
        rb[tid][2] = fmaxf(x2 - x1, 1.0f) * (1.0f / 14.0f);
        rb[tid][3] = fmaxf(y2 - y1, 1.0f) * (1.0f / 14.0f);
        if (tid == 0) snroi = wi[b];
    }
    __syncthreads();

    const int nroi  = snroi;
    const int ntask = nroi * 14;
    const size_t obase0 = ((size_t)c * 16 + 2 * tp) * 49;

    for (int task = tid; task < ntask; task += 512) {
        int r    = task / 14;
        int rem  = task - r * 14;
        int half = rem / 7;
        int ph   = rem - half * 7;
        int k = rlist[r];
        float x1 = rb[r][0], y1 = rb[r][1], bw = rb[r][2], bh = rb[r][3];

        // ---- y metadata: 2 samples -> 3-row factored weights (mask folded)
        float ys0 = fmaf((float)(2 * ph) + 0.5f, bh, y1);
        float ys1 = ys0 + bh;
        float my0 = (ys0 >= -1.0f && ys0 <= 64.0f) ? 1.0f : 0.0f;
        float my1 = (ys1 >= -1.0f && ys1 <= 64.0f) ? 1.0f : 0.0f;
        float yc0 = fminf(fmaxf(ys0, 0.0f), 63.0f);
        float yc1 = fminf(fmaxf(ys1, 0.0f), 63.0f);
        int y00 = min((int)yc0, 62);
        int y01 = min((int)yc1, 62);       // y01 in {y00, y00+1} since bh <= 1
        float ly0 = yc0 - (float)y00, ly1 = yc1 - (float)y01;
        float h0 = (1.0f - ly0) * my0, l0 = ly0 * my0;
        float h1 = (1.0f - ly1) * my1, l1 = ly1 * my1;
        bool dy = (y01 != y00);
        float yw0 = h0 + (dy ? 0.0f : h1);
        float yw1 = l0 + (dy ? h1 : l1);
        float yw2 = dy ? l1 : 0.0f;
        const float2* prow = (const float2*)plane[half] + y00 * LPH;

        const size_t ob = (((size_t)k << 12) + (obase0 >> 0) / 49 * 0 + 0) * 49
                        + obase0 + (size_t)half * 49 + ph * 7;  // k*4096*49 + ...
        #pragma unroll
        for (int pw = 0; pw < 7; ++pw) {
            // ---- x metadata: 2 samples -> 3-col weights (mask and 1/4 folded)
            float xs0 = fmaf((float)(2 * pw) + 0.5f, bw, x1);
            float xs1 = xs0 + bw;
            float mx0 = (xs0 >= -1.0f && xs0 <= 64.0f) ? 0.25f : 0.0f;
            float mx1 = (xs1 >= -1.0f && xs1 <= 64.0f) ? 0.25f : 0.0f;
            float xc0 = fminf(fmaxf(xs0, 0.0f), 63.0f);
            float xc1 = fminf(fmaxf(xs1, 0.0f), 63.0f);
            int x00 = min((int)xc0, 62);
            int x01 = min((int)xc1, 62);   // x01 in {x00, x00+1}
            float lx0 = xc0 - (float)x00, lx1 = xc1 - (float)x01;
            float a0 = (1.0f - lx0) * mx0, b0w = lx0 * mx0;
            float a1 = (1.0f - lx1) * mx1, b1w = lx1 * mx1;
            bool dx = (x01 != x00);
            float xw0 = a0  + (dx ? 0.0f : a1);
            float xw1 = b0w + (dx ? a1 : b1w);
            float xw2 = dx ? b1w : 0.0f;
            // shift into the even-aligned 4-col window
            bool odd = (x00 & 1);
            float w0 = odd ? 0.0f : xw0;
            float w1 = odd ? xw0 : xw1;
            float w2 = odd ? xw1 : xw2;
            float w3 = odd ? xw2 : 0.0f;
            int xb2 = x00 >> 1;            // float2 index of aligned window base

            float2 r0a = prow[xb2],           r0b = prow[xb2 + 1];
            float2 r1a = prow[xb2 + LPH],     r1b = prow[xb2 + LPH + 1];
            float2 r2a = prow[xb2 + 2 * LPH], r2b = prow[xb2 + 2 * LPH + 1];
            float s0 = w0 * r0a.x + w1 * r0a.y + w2 * r0b.x + w3 * r0b.y;
            float s1 = w0 * r1a.x + w1 * r1a.y + w2 * r1b.x + w3 * r1b.y;
            float s2 = w0 * r2a.x + w1 * r2a.y + w2 * r2b.x + w3 * r2b.y;
            out[ob + pw] = yw0 * s0 + yw1 * s1 + yw2 * s2;
        }
    }
}

extern "C" void kernel_launch(void* const* d_in, const int* in_sizes, int n_in,
                              void* d_out, int out_size, void* d_ws, size_t ws_size,
                              hipStream_t stream) {
    const float* x    = (const float*)d_in[0];
    const float* rois = (const float*)d_in[1];
    float* out = (float*)d_out;
    int*   wi  = (int*)d_ws;
    pooler_pre<<<1, 128, 0, stream>>>(rois, wi);
    pooler_main<<<2 * 256 * 8, 512, 0, stream>>>(x, rois, wi, out);
}